// Round 5
// baseline (514.815 us; speedup 1.0000x reference)
//
#include <hip/hip_runtime.h>

typedef unsigned short u16;

#define NTOK 8192
#define HD   1024
#define NEXP 8
#define CAP  2560   // ceil(1.25 * 8192 * 2 / 8) == 2560 == 20 * 128 tiles exactly

typedef __bf16 bf16x8 __attribute__((ext_vector_type(8)));
typedef float  f32x4  __attribute__((ext_vector_type(4)));

__device__ __forceinline__ u16 f2bf(float f){
  union { float f; unsigned u; } v; v.f = f;
  return (u16)((v.u + 0x7fffu + ((v.u >> 16) & 1u)) >> 16);   // RNE
}
__device__ __forceinline__ float bf2f(u16 h){
  union { unsigned u; float f; } v; v.u = ((unsigned)h) << 16; return v.f;
}

__device__ __forceinline__ void async16(const void* g, void* l){
  __builtin_amdgcn_global_load_lds((__attribute__((address_space(1))) void*)(g),
                                   (__attribute__((address_space(3))) void*)(l), 16, 0, 0);
}

// ---------------- prep: 6 weight casts + router (x-cast fused into router) ----------------
// blocks [0,2048): router (4 tokens/block) — also writes x_bf and atomically builds
//                  chunk_hist (order-independent counts; chunk_hist pre-zeroed via memsetAsync)
// blocks [2048,32768): segmented float4 cast of the 6 weight tensors
__global__ __launch_bounds__(256)
void prep_kernel(const float* __restrict__ x, const float* __restrict__ gate_w,
                 const float* __restrict__ we_gate, const float* __restrict__ we_up,
                 const float* __restrict__ we_down, const float* __restrict__ ws_gate,
                 const float* __restrict__ ws_up, const float* __restrict__ ws_down,
                 u16* __restrict__ x_bf, u16* __restrict__ wg_bf, u16* __restrict__ wu_bf,
                 u16* __restrict__ wd_bf, u16* __restrict__ wsg_bf, u16* __restrict__ wsu_bf,
                 u16* __restrict__ wsd_bf,
                 int* __restrict__ topk_idx, float* __restrict__ topk_w,
                 int* __restrict__ chunk_hist){
  __shared__ float gw[NEXP * HD];
  int bid = blockIdx.x;
  int t = threadIdx.x;
  if (bid < 2048){
    // ---- router (fp64 logits, top-2, normalized weights) + x cast ----
    for (int i = t; i < NEXP * HD; i += 256) gw[i] = gate_w[i];
    __syncthreads();
    int wave = t >> 6, l = t & 63;
    int tok = bid * 4 + wave;
    const float* xr = x + (size_t)tok * HD;
    u16* xbr = x_bf + (size_t)tok * HD;
    double acc[NEXP];
#pragma unroll
    for (int e = 0; e < NEXP; e++) acc[e] = 0.0;
    for (int j = 0; j < 16; j++){
      int h = j * 64 + l;
      float xf = xr[h];
      xbr[h] = f2bf(xf);                       // fused x -> bf16 cast
      double xv = (double)xf;
#pragma unroll
      for (int e = 0; e < NEXP; e++) acc[e] += xv * (double)gw[e * HD + h];
    }
#pragma unroll
    for (int e = 0; e < NEXP; e++){
      double v = acc[e];
#pragma unroll
      for (int off = 32; off > 0; off >>= 1) v += __shfl_down(v, off, 64);
      acc[e] = v;
    }
    if (l == 0){
      int i0 = 0; double l0 = acc[0];
#pragma unroll
      for (int e = 1; e < NEXP; e++) if (acc[e] > l0){ l0 = acc[e]; i0 = e; }
      int i1 = -1; double l1 = -1e300;
#pragma unroll
      for (int e = 0; e < NEXP; e++) if (e != i0 && acc[e] > l1){ l1 = acc[e]; i1 = e; }
      double e1 = exp(l1 - l0);
      double s  = 1.0 + e1;
      topk_idx[tok * 2 + 0] = i0;
      topk_idx[tok * 2 + 1] = i1;
      topk_w [tok * 2 + 0] = (float)(1.0 / s);
      topk_w [tok * 2 + 1] = (float)(e1 / s);
      int chunk = tok >> 7;                    // 256 slots = 128 tokens per chunk
      atomicAdd(&chunk_hist[chunk * NEXP + i0], 1);
      atomicAdd(&chunk_hist[chunk * NEXP + i1], 1);
    }
  } else {
    // ---- weight casts (segments are multiples of 256 float4s; blocks never straddle) ----
    long long g = (long long)(bid - 2048) * 256 + t;   // float4 index
    const float4* s; ushort4* d; long long off;
    if      (g <  2097152){ s = (const float4*)we_gate; d = (ushort4*)wg_bf;  off = 0; }
    else if (g <  4194304){ s = (const float4*)we_up;   d = (ushort4*)wu_bf;  off = 2097152; }
    else if (g <  6291456){ s = (const float4*)we_down; d = (ushort4*)wd_bf;  off = 4194304; }
    else if (g <  6815744){ s = (const float4*)ws_gate; d = (ushort4*)wsg_bf; off = 6291456; }
    else if (g <  7340032){ s = (const float4*)ws_up;   d = (ushort4*)wsu_bf; off = 6815744; }
    else                  { s = (const float4*)ws_down; d = (ushort4*)wsd_bf; off = 7340032; }
    long long i = g - off;
    float4 v = s[i];
    ushort4 o;
    o.x = f2bf(v.x); o.y = f2bf(v.y); o.z = f2bf(v.z); o.w = f2bf(v.w);
    d[i] = o;
  }
}

// ---------------- capacity scan pass 2 (stable): rank = chunk-prefix + ballot rank ----------------
__global__ __launch_bounds__(256)
void scan_p2(const int* __restrict__ topk_idx, const float* __restrict__ topk_w,
             const int* __restrict__ chunk_hist,
             int* __restrict__ tok_list, float* __restrict__ w_list,
             int* __restrict__ slot_map, int* __restrict__ ne){
  __shared__ int hist_s[64 * NEXP];
  __shared__ int base_s[NEXP];
  __shared__ int wcnt[4 * NEXP];
  int t = threadIdx.x, w = t >> 6, l = t & 63;
  int chunk = blockIdx.x;
#pragma unroll
  for (int i = 0; i < 2; i++) hist_s[i * 256 + t] = chunk_hist[i * 256 + t];
  __syncthreads();
  if (t < NEXP){
    int b = 0, tot = 0;
    for (int c = 0; c < 64; c++){
      if (c == chunk) b = tot;
      tot += hist_s[c * NEXP + t];
    }
    base_s[t] = b;
    if (chunk == 0) ne[t] = tot < CAP ? tot : CAP;
  }
  int slot = chunk * 256 + t;
  int my_e = topk_idx[slot];
  float my_w = topk_w[slot];
  unsigned long long mymask = 0;
#pragma unroll
  for (int e = 0; e < NEXP; e++){
    unsigned long long m = __ballot(my_e == e);
    if (my_e == e) mymask = m;
    if (l == e) wcnt[w * NEXP + e] = __popcll(m);
  }
  __syncthreads();
  if (t < NEXP){
    int run = 0;
#pragma unroll
    for (int w2 = 0; w2 < 4; w2++){ int v = wcnt[w2 * NEXP + t]; wcnt[w2 * NEXP + t] = run; run += v; }
  }
  __syncthreads();
  int pos = base_s[my_e] + wcnt[w * NEXP + my_e] + __popcll(mymask & ((1ull << l) - 1ull));
  if (pos < CAP){
    tok_list[my_e * CAP + pos] = slot >> 1;
    w_list [my_e * CAP + pos] = my_w;
    slot_map[slot] = my_e * CAP + pos;
  } else {
    slot_map[slot] = -1;
  }
}

// ---------------- merged SwiGLU GEMM: routed (XCD-pinned experts) + shared ----------------
// blocks [0,2560): routed  e=bid&7, r=bid>>3: m0=(r>>4)*128, n0=(r&15)*64
// blocks [2560,4608): shared b2: n0=(b2/64)*64, m0=(b2%64)*128
__global__ __launch_bounds__(256)
void gu_kernel(const u16* __restrict__ x_bf,
               const u16* __restrict__ wg, const u16* __restrict__ wu,
               const u16* __restrict__ wsg, const u16* __restrict__ wsu,
               u16* __restrict__ Hr, u16* __restrict__ Hs,
               const int* __restrict__ tok_list, const int* __restrict__ ne)
{
  __shared__ u16 As[128 * 64];
  __shared__ u16 Bs[128 * 64];

  const int bid = blockIdx.x;
  const bool routed = bid < 2560;
  int m0, n0, ldc, n_valid;
  const u16 *B0, *B1;
  u16* C;
  const int* tl = nullptr;
  if (routed){
    int e = bid & 7, r = bid >> 3;
    m0 = (r >> 4) * 128; n0 = (r & 15) * 64;
    B0 = wg + (size_t)e * (1024 * 1024);
    B1 = wu + (size_t)e * (1024 * 1024);
    C  = Hr + (size_t)e * (CAP * 1024);
    ldc = 1024;
    n_valid = ne[e];
    tl = tok_list + e * CAP;
    if (m0 >= n_valid) return;
  } else {
    int b2 = bid - 2560;
    n0 = (b2 / 64) * 64; m0 = (b2 % 64) * 128;
    B0 = wsg; B1 = wsu; C = Hs; ldc = 2048; n_valid = 1 << 30;
  }

  const int tid = threadIdx.x;
  const int wv  = tid >> 6;
  const int l   = tid & 63;
  const int lr  = l >> 3;             // row within 8-row chunk
  const int cb  = (l & 7) ^ lr;       // XOR-swizzled col-block (16B units)

  const u16* aptr[4];
  const u16* bptr[4];
#pragma unroll
  for (int i = 0; i < 4; i++){
    int chunk = i * 4 + wv;
    int arow  = m0 + chunk * 8 + lr;
    if (routed){
      int r2 = arow < n_valid ? arow : (n_valid - 1);
      aptr[i] = x_bf + (size_t)tl[r2] * 1024 + cb * 8;
    } else {
      aptr[i] = x_bf + (size_t)arow * 1024 + cb * 8;
    }
    int rn = chunk * 8 + lr;          // B tile row 0..127
    int w  = rn >> 6;                 // which wave-half of N
    int jq = (rn >> 4) & 3;           // 0,1 = gate ; 2,3 = up (uniform per chunk)
    int rl = rn & 15;
    int icol = n0 + w * 32 + (jq & 1) * 16 + rl;
    bptr[i] = ((jq < 2) ? B0 : B1) + (size_t)icol * 1024 + cb * 8;
  }

  const int wm = wv & 1, wn = wv >> 1;
  const int col = l & 15, quad = l >> 4;
  const int rr = col & 7, ch = col >> 3;

  f32x4 acc[4][4];
#pragma unroll
  for (int i = 0; i < 4; i++)
#pragma unroll
    for (int j = 0; j < 4; j++)
      acc[i][j] = (f32x4){0.f, 0.f, 0.f, 0.f};

  for (int k0 = 0; k0 < 1024; k0 += 64){
#pragma unroll
    for (int i = 0; i < 4; i++){
      int chunk = i * 4 + wv;
      async16(aptr[i] + k0, &As[chunk * 512 + l * 8]);
      async16(bptr[i] + k0, &Bs[chunk * 512 + l * 8]);
    }
    __syncthreads();
#pragma unroll
    for (int s = 0; s < 2; s++){
      const int so = (rr * 8 + ((quad + s * 4) ^ rr)) * 8;   // swizzled fragment offset
      bf16x8 a[4], b[4];
#pragma unroll
      for (int i = 0; i < 4; i++) a[i] = *(const bf16x8*)&As[(wm * 8 + i * 2 + ch) * 512 + so];
#pragma unroll
      for (int j = 0; j < 4; j++) b[j] = *(const bf16x8*)&Bs[(wn * 8 + j * 2 + ch) * 512 + so];
#pragma unroll
      for (int i = 0; i < 4; i++)
#pragma unroll
        for (int j = 0; j < 4; j++)
          acc[i][j] = __builtin_amdgcn_mfma_f32_16x16x32_bf16(a[i], b[j], acc[i][j], 0, 0, 0);
    }
    __syncthreads();
  }

  // epilogue: silu(g)*u -> bf16
#pragma unroll
  for (int i = 0; i < 4; i++)
#pragma unroll
    for (int r = 0; r < 4; r++){
      int row = m0 + wm * 64 + i * 16 + quad * 4 + r;
#pragma unroll
      for (int j = 0; j < 2; j++){
        int cg = n0 + wn * 32 + j * 16 + col;
        float g = acc[i][j][r], u = acc[i][j + 2][r];
        float h = (g / (1.f + __expf(-g))) * u;
        C[(size_t)row * ldc + cg] = f2bf(h);
      }
    }
}

// ---------------- merged down-proj, 5:2 interleaved for makespan balance ----------------
// bid%7 in {0..4}: routed rid=(bid/7)*5+bid%7 in [0,1280): e=rid&7, r=rid>>3,
//                  m0=(r>>3)*128, n0=(r&7)*128, K=1024; Ebuf = w * (Hr @ wd^T), bf16
// bid%7 in {5,6}: shared sid=(bid/7)*2+(bid%7-5) in [0,512): n0=(sid&7)*128,
//                  m0=(sid>>3)*128, K=2048; out = Hs @ wsd^T, fp32 plain store
__global__ __launch_bounds__(256)
void down_kernel(const u16* __restrict__ Hr, const u16* __restrict__ wd,
                 const u16* __restrict__ Hs, const u16* __restrict__ wsd,
                 u16* __restrict__ Ebuf, float* __restrict__ out,
                 const float* __restrict__ w_list, const int* __restrict__ ne)
{
  __shared__ u16 As[128 * 64];
  __shared__ u16 Bs[128 * 64];

  const int bid = blockIdx.x;
  const int m7 = bid % 7, d7 = bid / 7;
  const bool routed = m7 < 5;
  int m0, n0, n_valid, K, e = 0;
  const u16 *Ab, *Bb;
  if (routed){
    int rid = d7 * 5 + m7;
    e = rid & 7; int r = rid >> 3;
    m0 = (r >> 3) * 128; n0 = (r & 7) * 128;
    Ab = Hr + (size_t)e * (CAP * 1024);
    Bb = wd + (size_t)e * (1024 * 1024);
    K = 1024;
    n_valid = ne[e];
    if (m0 >= n_valid) return;
  } else {
    int sid = d7 * 2 + (m7 - 5);
    n0 = (sid & 7) * 128; m0 = (sid >> 3) * 128;
    Ab = Hs; Bb = wsd; K = 2048; n_valid = 1 << 30;
  }

  const int tid = threadIdx.x;
  const int wv  = tid >> 6;
  const int l   = tid & 63;
  const int lr  = l >> 3;
  const int cb  = (l & 7) ^ lr;

  const u16* aptr[4];
  const u16* bptr[4];
#pragma unroll
  for (int i = 0; i < 4; i++){
    int chunk = i * 4 + wv;
    aptr[i] = Ab + (size_t)(m0 + chunk * 8 + lr) * K + cb * 8;
    bptr[i] = Bb + (size_t)(n0 + chunk * 8 + lr) * K + cb * 8;
  }

  const int wm = wv & 1, wn = wv >> 1;
  const int col = l & 15, quad = l >> 4;
  const int rr = col & 7, ch = col >> 3;

  f32x4 acc[4][4];
#pragma unroll
  for (int i = 0; i < 4; i++)
#pragma unroll
    for (int j = 0; j < 4; j++)
      acc[i][j] = (f32x4){0.f, 0.f, 0.f, 0.f};

  for (int k0 = 0; k0 < K; k0 += 64){
#pragma unroll
    for (int i = 0; i < 4; i++){
      int chunk = i * 4 + wv;
      async16(aptr[i] + k0, &As[chunk * 512 + l * 8]);
      async16(bptr[i] + k0, &Bs[chunk * 512 + l * 8]);
    }
    __syncthreads();
#pragma unroll
    for (int s = 0; s < 2; s++){
      const int so = (rr * 8 + ((quad + s * 4) ^ rr)) * 8;
      bf16x8 a[4], b[4];
#pragma unroll
      for (int i = 0; i < 4; i++) a[i] = *(const bf16x8*)&As[(wm * 8 + i * 2 + ch) * 512 + so];
#pragma unroll
      for (int j = 0; j < 4; j++) b[j] = *(const bf16x8*)&Bs[(wn * 8 + j * 2 + ch) * 512 + so];
#pragma unroll
      for (int i = 0; i < 4; i++)
#pragma unroll
        for (int j = 0; j < 4; j++)
          acc[i][j] = __builtin_amdgcn_mfma_f32_16x16x32_bf16(a[i], b[j], acc[i][j], 0, 0, 0);
    }
    __syncthreads();
  }

  if (routed){
    u16* C = Ebuf + (size_t)e * (CAP * 1024);
    const float* wl = w_list + e * CAP;
#pragma unroll
    for (int i = 0; i < 4; i++)
#pragma unroll
      for (int r = 0; r < 4; r++){
        int row = m0 + wm * 64 + i * 16 + quad * 4 + r;
        if (row < n_valid){
          float wgt = wl[row];
#pragma unroll
          for (int j = 0; j < 4; j++){
            int cg = n0 + wn * 64 + j * 16 + col;
            C[(size_t)row * 1024 + cg] = f2bf(wgt * acc[i][j][r]);
          }
        }
      }
  } else {
#pragma unroll
    for (int i = 0; i < 4; i++)
#pragma unroll
      for (int r = 0; r < 4; r++){
        int row = m0 + wm * 64 + i * 16 + quad * 4 + r;
#pragma unroll
        for (int j = 0; j < 4; j++){
          int cg = n0 + wn * 64 + j * 16 + col;
          out[(size_t)row * 1024 + cg] = acc[i][j][r];
        }
      }
  }
}

// ---------------- combine: out[tok] += Ebuf[slot0] + Ebuf[slot1] (4 float4/thread) ----------------
__global__ __launch_bounds__(256)
void combine_kernel(float* __restrict__ out, const u16* __restrict__ Ebuf,
                    const int* __restrict__ slot_map){
  long long g0 = (long long)blockIdx.x * 256 + threadIdx.x;
#pragma unroll
  for (int k = 0; k < 4; k++){
    long long g = g0 + (long long)k * 524288;   // 2M float4 total / 4
    int row = (int)(g >> 8);                    // 256 float4 per 1024-col row
    int c4  = (int)(g & 255);
    int s0 = slot_map[row * 2 + 0];
    int s1 = slot_map[row * 2 + 1];
    float4 v = ((float4*)out)[g];
    if (s0 >= 0){
      ushort4 a = ((const ushort4*)Ebuf)[(size_t)s0 * 256 + c4];
      v.x += bf2f(a.x); v.y += bf2f(a.y); v.z += bf2f(a.z); v.w += bf2f(a.w);
    }
    if (s1 >= 0){
      ushort4 a = ((const ushort4*)Ebuf)[(size_t)s1 * 256 + c4];
      v.x += bf2f(a.x); v.y += bf2f(a.y); v.z += bf2f(a.z); v.w += bf2f(a.w);
    }
    ((float4*)out)[g] = v;
  }
}

extern "C" void kernel_launch(void* const* d_in, const int* in_sizes, int n_in,
                              void* d_out, int out_size, void* d_ws, size_t ws_size,
                              hipStream_t stream){
  const float* x       = (const float*)d_in[0];
  const float* gate_w  = (const float*)d_in[1];
  const float* we_gate = (const float*)d_in[2];
  const float* we_up   = (const float*)d_in[3];
  const float* we_down = (const float*)d_in[4];
  const float* ws_gate = (const float*)d_in[5];
  const float* ws_up   = (const float*)d_in[6];
  const float* ws_down = (const float*)d_in[7];
  float* out = (float*)d_out;

  // ws layout. Ebuf aliases [wg_bf .. wsu_bf] (41,943,040 B, exact): gate/up weights
  // are dead after gu_kernel; Ebuf is written by down_kernel afterwards.
  char* p = (char*)d_ws;
  u16* x_bf   = (u16*)p; p += (size_t)NTOK * HD * 2;
  u16* wg_bf  = (u16*)p; p += (size_t)NEXP * 1024 * 1024 * 2;
  u16* wu_bf  = (u16*)p; p += (size_t)NEXP * 1024 * 1024 * 2;
  u16* wsg_bf = (u16*)p; p += (size_t)2048 * 1024 * 2;
  u16* wsu_bf = (u16*)p; p += (size_t)2048 * 1024 * 2;
  u16* wd_bf  = (u16*)p; p += (size_t)NEXP * 1024 * 1024 * 2;
  u16* wsd_bf = (u16*)p; p += (size_t)1024 * 2048 * 2;
  u16* Hr     = (u16*)p; p += (size_t)NEXP * CAP * 1024 * 2;  // routed H [8*2560, 1024]
  u16* Hs     = (u16*)p; p += (size_t)NTOK * 2048 * 2;        // shared H [8192, 2048]
  int*   topk_idx   = (int*)p;   p += (size_t)NTOK * 2 * 4;
  float* topk_w     = (float*)p; p += (size_t)NTOK * 2 * 4;
  int*   tok_list   = (int*)p;   p += (size_t)NEXP * CAP * 4;
  float* w_list     = (float*)p; p += (size_t)NEXP * CAP * 4;
  int*   slot_map   = (int*)p;   p += (size_t)NTOK * 2 * 4;
  int*   chunk_hist = (int*)p;   p += 64 * NEXP * 4;
  int*   ne         = (int*)p;   p += 128;
  u16* Ebuf = wg_bf;             // alias (see note above)

  // phase 0: zero chunk_hist (router blocks atomically accumulate into it)
  hipMemsetAsync(chunk_hist, 0, 64 * NEXP * 4, stream);

  // phase 1: weight casts + router (+x cast, +chunk_hist)  [32768 blocks]
  prep_kernel<<<dim3(32768), dim3(256), 0, stream>>>(
      x, gate_w, we_gate, we_up, we_down, ws_gate, ws_up, ws_down,
      x_bf, wg_bf, wu_bf, wd_bf, wsg_bf, wsu_bf, wsd_bf, topk_idx, topk_w, chunk_hist);

  // phase 2: stable capacity-scan ranking
  scan_p2<<<dim3(64), dim3(256), 0, stream>>>(topk_idx, topk_w, chunk_hist,
                                              tok_list, w_list, slot_map, ne);

  // phase 3: merged SwiGLU GEMMs (routed 2560 + shared 2048 blocks)
  gu_kernel<<<dim3(4608), dim3(256), 0, stream>>>(
      x_bf, wg_bf, wu_bf, wsg_bf, wsu_bf, Hr, Hs, tok_list, ne);

  // phase 4: merged down-proj, 5:2 interleaved (routed 1280 -> Ebuf, shared 512 -> out)
  down_kernel<<<dim3(1792), dim3(256), 0, stream>>>(
      Hr, wd_bf, Hs, wsd_bf, Ebuf, out, w_list, ne);

  // phase 5: combine routed contributions into out
  combine_kernel<<<dim3(2048), dim3(256), 0, stream>>>(out, Ebuf, slot_map);
}

// Round 6
// 496.962 us; speedup vs baseline: 1.0359x; 1.0359x over previous
//
#include <hip/hip_runtime.h>

typedef unsigned short u16;

#define NTOK 8192
#define HD   1024
#define NEXP 8
#define CAP  2560   // ceil(1.25 * 8192 * 2 / 8) == 2560 == 20 * 128 tiles exactly

typedef __bf16 bf16x8 __attribute__((ext_vector_type(8)));
typedef float  f32x4  __attribute__((ext_vector_type(4)));

__device__ __forceinline__ u16 f2bf(float f){
  union { float f; unsigned u; } v; v.f = f;
  return (u16)((v.u + 0x7fffu + ((v.u >> 16) & 1u)) >> 16);   // RNE
}
__device__ __forceinline__ float bf2f(u16 h){
  union { unsigned u; float f; } v; v.u = ((unsigned)h) << 16; return v.f;
}

__device__ __forceinline__ void async16(const void* g, void* l){
  __builtin_amdgcn_global_load_lds((__attribute__((address_space(1))) void*)(g),
                                   (__attribute__((address_space(3))) void*)(l), 16, 0, 0);
}

// ---------------- prep: all 7 fp32->bf16 casts + router fused in one launch ----------------
__global__ __launch_bounds__(256)
void prep_kernel(const float* __restrict__ x, const float* __restrict__ gate_w,
                 const float* __restrict__ we_gate, const float* __restrict__ we_up,
                 const float* __restrict__ we_down, const float* __restrict__ ws_gate,
                 const float* __restrict__ ws_up, const float* __restrict__ ws_down,
                 u16* __restrict__ x_bf, u16* __restrict__ wg_bf, u16* __restrict__ wu_bf,
                 u16* __restrict__ wd_bf, u16* __restrict__ wsg_bf, u16* __restrict__ wsu_bf,
                 u16* __restrict__ wsd_bf,
                 int* __restrict__ topk_idx, float* __restrict__ topk_w){
  __shared__ float gw[NEXP * HD];
  int bid = blockIdx.x;
  int t = threadIdx.x;
  if (bid < 2048){
    // ---- router (4 tokens/block, fp64 logits, top-2, normalized weights) ----
    for (int i = t; i < NEXP * HD; i += 256) gw[i] = gate_w[i];
    __syncthreads();
    int wave = t >> 6, l = t & 63;
    int tok = bid * 4 + wave;
    const float* xr = x + (size_t)tok * HD;
    double acc[NEXP];
#pragma unroll
    for (int e = 0; e < NEXP; e++) acc[e] = 0.0;
    for (int j = 0; j < 16; j++){
      int h = j * 64 + l;
      double xv = (double)xr[h];
#pragma unroll
      for (int e = 0; e < NEXP; e++) acc[e] += xv * (double)gw[e * HD + h];
    }
#pragma unroll
    for (int e = 0; e < NEXP; e++){
      double v = acc[e];
#pragma unroll
      for (int off = 32; off > 0; off >>= 1) v += __shfl_down(v, off, 64);
      acc[e] = v;
    }
    if (l == 0){
      int i0 = 0; double l0 = acc[0];
#pragma unroll
      for (int e = 1; e < NEXP; e++) if (acc[e] > l0){ l0 = acc[e]; i0 = e; }
      int i1 = -1; double l1 = -1e300;
#pragma unroll
      for (int e = 0; e < NEXP; e++) if (e != i0 && acc[e] > l1){ l1 = acc[e]; i1 = e; }
      double e1 = exp(l1 - l0);
      double s  = 1.0 + e1;
      topk_idx[tok * 2 + 0] = i0;
      topk_idx[tok * 2 + 1] = i1;
      topk_w [tok * 2 + 0] = (float)(1.0 / s);
      topk_w [tok * 2 + 1] = (float)(e1 / s);
    }
  } else {
    // ---- cast (segments are multiples of 256 float4s; blocks never straddle) ----
    long long g = (long long)(bid - 2048) * 256 + t;   // float4 index
    const float4* s; ushort4* d; long long off;
    if      (g <  2097152){ s = (const float4*)x;       d = (ushort4*)x_bf;   off = 0; }
    else if (g <  4194304){ s = (const float4*)we_gate; d = (ushort4*)wg_bf;  off = 2097152; }
    else if (g <  6291456){ s = (const float4*)we_up;   d = (ushort4*)wu_bf;  off = 4194304; }
    else if (g <  8388608){ s = (const float4*)we_down; d = (ushort4*)wd_bf;  off = 6291456; }
    else if (g <  8912896){ s = (const float4*)ws_gate; d = (ushort4*)wsg_bf; off = 8388608; }
    else if (g <  9437184){ s = (const float4*)ws_up;   d = (ushort4*)wsu_bf; off = 8912896; }
    else                  { s = (const float4*)ws_down; d = (ushort4*)wsd_bf; off = 9437184; }
    long long i = g - off;
    float4 v = s[i];
    ushort4 o;
    o.x = f2bf(v.x); o.y = f2bf(v.y); o.z = f2bf(v.z); o.w = f2bf(v.w);
    d[i] = o;
  }
}

// ---------------- parallel capacity scan (stable), 2 passes of 64 blocks ----------------
__global__ __launch_bounds__(256)
void scan_p1(const int* __restrict__ topk_idx, int* __restrict__ chunk_hist){
  __shared__ int wcnt[4 * NEXP];
  int t = threadIdx.x, w = t >> 6, l = t & 63;
  int my_e = topk_idx[blockIdx.x * 256 + t];
#pragma unroll
  for (int e = 0; e < NEXP; e++){
    unsigned long long m = __ballot(my_e == e);
    if (l == e) wcnt[w * NEXP + e] = __popcll(m);
  }
  __syncthreads();
  if (t < NEXP){
    int s = 0;
#pragma unroll
    for (int w2 = 0; w2 < 4; w2++) s += wcnt[w2 * NEXP + t];
    chunk_hist[blockIdx.x * NEXP + t] = s;
  }
}

__global__ __launch_bounds__(256)
void scan_p2(const int* __restrict__ topk_idx, const float* __restrict__ topk_w,
             const int* __restrict__ chunk_hist,
             int* __restrict__ tok_list, float* __restrict__ w_list,
             int* __restrict__ slot_map, int* __restrict__ ne){
  __shared__ int hist_s[64 * NEXP];
  __shared__ int base_s[NEXP];
  __shared__ int wcnt[4 * NEXP];
  int t = threadIdx.x, w = t >> 6, l = t & 63;
  int chunk = blockIdx.x;
#pragma unroll
  for (int i = 0; i < 2; i++) hist_s[i * 256 + t] = chunk_hist[i * 256 + t];
  __syncthreads();
  if (t < NEXP){
    int b = 0, tot = 0;
    for (int c = 0; c < 64; c++){
      if (c == chunk) b = tot;
      tot += hist_s[c * NEXP + t];
    }
    base_s[t] = b;
    if (chunk == 0) ne[t] = tot < CAP ? tot : CAP;
  }
  int slot = chunk * 256 + t;
  int my_e = topk_idx[slot];
  float my_w = topk_w[slot];
  unsigned long long mymask = 0;
#pragma unroll
  for (int e = 0; e < NEXP; e++){
    unsigned long long m = __ballot(my_e == e);
    if (my_e == e) mymask = m;
    if (l == e) wcnt[w * NEXP + e] = __popcll(m);
  }
  __syncthreads();
  if (t < NEXP){
    int run = 0;
#pragma unroll
    for (int w2 = 0; w2 < 4; w2++){ int v = wcnt[w2 * NEXP + t]; wcnt[w2 * NEXP + t] = run; run += v; }
  }
  __syncthreads();
  int pos = base_s[my_e] + wcnt[w * NEXP + my_e] + __popcll(mymask & ((1ull << l) - 1ull));
  if (pos < CAP){
    tok_list[my_e * CAP + pos] = slot >> 1;
    w_list [my_e * CAP + pos] = my_w;
    slot_map[slot] = my_e * CAP + pos;
  } else {
    slot_map[slot] = -1;
  }
}

// ---------------- merged SwiGLU GEMM: routed (XCD-pinned experts) + shared ----------------
// blocks [0,2560): routed  e=bid&7, r=bid>>3: m0=(r>>4)*128, n0=(r&15)*64
// blocks [2560,4608): shared b2: n0=(b2/64)*64, m0=(b2%64)*128
__global__ __launch_bounds__(256)
void gu_kernel(const u16* __restrict__ x_bf,
               const u16* __restrict__ wg, const u16* __restrict__ wu,
               const u16* __restrict__ wsg, const u16* __restrict__ wsu,
               u16* __restrict__ Hr, u16* __restrict__ Hs,
               const int* __restrict__ tok_list, const int* __restrict__ ne)
{
  __shared__ u16 As[128 * 64];
  __shared__ u16 Bs[128 * 64];

  const int bid = blockIdx.x;
  const bool routed = bid < 2560;
  int m0, n0, ldc, n_valid;
  const u16 *B0, *B1;
  u16* C;
  const int* tl = nullptr;
  if (routed){
    int e = bid & 7, r = bid >> 3;
    m0 = (r >> 4) * 128; n0 = (r & 15) * 64;
    B0 = wg + (size_t)e * (1024 * 1024);
    B1 = wu + (size_t)e * (1024 * 1024);
    C  = Hr + (size_t)e * (CAP * 1024);
    ldc = 1024;
    n_valid = ne[e];
    tl = tok_list + e * CAP;
    if (m0 >= n_valid) return;
  } else {
    int b2 = bid - 2560;
    n0 = (b2 / 64) * 64; m0 = (b2 % 64) * 128;
    B0 = wsg; B1 = wsu; C = Hs; ldc = 2048; n_valid = 1 << 30;
  }

  const int tid = threadIdx.x;
  const int wv  = tid >> 6;
  const int l   = tid & 63;
  const int lr  = l >> 3;             // row within 8-row chunk
  const int cb  = (l & 7) ^ lr;       // XOR-swizzled col-block (16B units)

  const u16* aptr[4];
  const u16* bptr[4];
#pragma unroll
  for (int i = 0; i < 4; i++){
    int chunk = i * 4 + wv;
    int arow  = m0 + chunk * 8 + lr;
    if (routed){
      int r2 = arow < n_valid ? arow : (n_valid - 1);
      aptr[i] = x_bf + (size_t)tl[r2] * 1024 + cb * 8;
    } else {
      aptr[i] = x_bf + (size_t)arow * 1024 + cb * 8;
    }
    int rn = chunk * 8 + lr;          // B tile row 0..127
    int w  = rn >> 6;                 // which wave-half of N
    int jq = (rn >> 4) & 3;           // 0,1 = gate ; 2,3 = up (uniform per chunk)
    int rl = rn & 15;
    int icol = n0 + w * 32 + (jq & 1) * 16 + rl;
    bptr[i] = ((jq < 2) ? B0 : B1) + (size_t)icol * 1024 + cb * 8;
  }

  const int wm = wv & 1, wn = wv >> 1;
  const int col = l & 15, quad = l >> 4;
  const int rr = col & 7, ch = col >> 3;

  f32x4 acc[4][4];
#pragma unroll
  for (int i = 0; i < 4; i++)
#pragma unroll
    for (int j = 0; j < 4; j++)
      acc[i][j] = (f32x4){0.f, 0.f, 0.f, 0.f};

  for (int k0 = 0; k0 < 1024; k0 += 64){
#pragma unroll
    for (int i = 0; i < 4; i++){
      int chunk = i * 4 + wv;
      async16(aptr[i] + k0, &As[chunk * 512 + l * 8]);
      async16(bptr[i] + k0, &Bs[chunk * 512 + l * 8]);
    }
    __syncthreads();
#pragma unroll
    for (int s = 0; s < 2; s++){
      const int so = (rr * 8 + ((quad + s * 4) ^ rr)) * 8;   // swizzled fragment offset
      bf16x8 a[4], b[4];
#pragma unroll
      for (int i = 0; i < 4; i++) a[i] = *(const bf16x8*)&As[(wm * 8 + i * 2 + ch) * 512 + so];
#pragma unroll
      for (int j = 0; j < 4; j++) b[j] = *(const bf16x8*)&Bs[(wn * 8 + j * 2 + ch) * 512 + so];
#pragma unroll
      for (int i = 0; i < 4; i++)
#pragma unroll
        for (int j = 0; j < 4; j++)
          acc[i][j] = __builtin_amdgcn_mfma_f32_16x16x32_bf16(a[i], b[j], acc[i][j], 0, 0, 0);
    }
    __syncthreads();
  }

  // epilogue: silu(g)*u -> bf16
#pragma unroll
  for (int i = 0; i < 4; i++)
#pragma unroll
    for (int r = 0; r < 4; r++){
      int row = m0 + wm * 64 + i * 16 + quad * 4 + r;
#pragma unroll
      for (int j = 0; j < 2; j++){
        int cg = n0 + wn * 32 + j * 16 + col;
        float g = acc[i][j][r], u = acc[i][j + 2][r];
        float h = (g / (1.f + __expf(-g))) * u;
        C[(size_t)row * ldc + cg] = f2bf(h);
      }
    }
}

// ---------------- merged down-proj, LPT order: shared (K=2048, 2x work) FIRST ----------------
// blocks [0,512):   shared sid=bid: n0=(sid&7)*128, m0=(sid>>3)*128, K=2048
//                   out = Hs @ wsd^T, fp32 plain store (combine adds routed after)
// blocks [512,1792): routed rid=bid-512: e=rid&7 (XCD-pinned), r=rid>>3,
//                   m0=(r>>3)*128, n0=(r&7)*128, K=1024
//                   Ebuf[slot] = w_list[slot] * (Hr @ wd^T), bf16
__global__ __launch_bounds__(256)
void down_kernel(const u16* __restrict__ Hr, const u16* __restrict__ wd,
                 const u16* __restrict__ Hs, const u16* __restrict__ wsd,
                 u16* __restrict__ Ebuf, float* __restrict__ out,
                 const float* __restrict__ w_list, const int* __restrict__ ne)
{
  __shared__ u16 As[128 * 64];
  __shared__ u16 Bs[128 * 64];

  const int bid = blockIdx.x;
  const bool routed = bid >= 512;
  int m0, n0, n_valid, K, e = 0;
  const u16 *Ab, *Bb;
  if (routed){
    int rid = bid - 512;
    e = rid & 7; int r = rid >> 3;
    m0 = (r >> 3) * 128; n0 = (r & 7) * 128;
    Ab = Hr + (size_t)e * (CAP * 1024);
    Bb = wd + (size_t)e * (1024 * 1024);
    K = 1024;
    n_valid = ne[e];
    if (m0 >= n_valid) return;
  } else {
    int sid = bid;
    n0 = (sid & 7) * 128; m0 = (sid >> 3) * 128;
    Ab = Hs; Bb = wsd; K = 2048; n_valid = 1 << 30;
  }

  const int tid = threadIdx.x;
  const int wv  = tid >> 6;
  const int l   = tid & 63;
  const int lr  = l >> 3;
  const int cb  = (l & 7) ^ lr;

  const u16* aptr[4];
  const u16* bptr[4];
#pragma unroll
  for (int i = 0; i < 4; i++){
    int chunk = i * 4 + wv;
    aptr[i] = Ab + (size_t)(m0 + chunk * 8 + lr) * K + cb * 8;
    bptr[i] = Bb + (size_t)(n0 + chunk * 8 + lr) * K + cb * 8;
  }

  const int wm = wv & 1, wn = wv >> 1;
  const int col = l & 15, quad = l >> 4;
  const int rr = col & 7, ch = col >> 3;

  f32x4 acc[4][4];
#pragma unroll
  for (int i = 0; i < 4; i++)
#pragma unroll
    for (int j = 0; j < 4; j++)
      acc[i][j] = (f32x4){0.f, 0.f, 0.f, 0.f};

  for (int k0 = 0; k0 < K; k0 += 64){
#pragma unroll
    for (int i = 0; i < 4; i++){
      int chunk = i * 4 + wv;
      async16(aptr[i] + k0, &As[chunk * 512 + l * 8]);
      async16(bptr[i] + k0, &Bs[chunk * 512 + l * 8]);
    }
    __syncthreads();
#pragma unroll
    for (int s = 0; s < 2; s++){
      const int so = (rr * 8 + ((quad + s * 4) ^ rr)) * 8;
      bf16x8 a[4], b[4];
#pragma unroll
      for (int i = 0; i < 4; i++) a[i] = *(const bf16x8*)&As[(wm * 8 + i * 2 + ch) * 512 + so];
#pragma unroll
      for (int j = 0; j < 4; j++) b[j] = *(const bf16x8*)&Bs[(wn * 8 + j * 2 + ch) * 512 + so];
#pragma unroll
      for (int i = 0; i < 4; i++)
#pragma unroll
        for (int j = 0; j < 4; j++)
          acc[i][j] = __builtin_amdgcn_mfma_f32_16x16x32_bf16(a[i], b[j], acc[i][j], 0, 0, 0);
    }
    __syncthreads();
  }

  if (routed){
    u16* C = Ebuf + (size_t)e * (CAP * 1024);
    const float* wl = w_list + e * CAP;
#pragma unroll
    for (int i = 0; i < 4; i++)
#pragma unroll
      for (int r = 0; r < 4; r++){
        int row = m0 + wm * 64 + i * 16 + quad * 4 + r;
        if (row < n_valid){
          float wgt = wl[row];
#pragma unroll
          for (int j = 0; j < 4; j++){
            int cg = n0 + wn * 64 + j * 16 + col;
            C[(size_t)row * 1024 + cg] = f2bf(wgt * acc[i][j][r]);
          }
        }
      }
  } else {
#pragma unroll
    for (int i = 0; i < 4; i++)
#pragma unroll
      for (int r = 0; r < 4; r++){
        int row = m0 + wm * 64 + i * 16 + quad * 4 + r;
#pragma unroll
        for (int j = 0; j < 4; j++){
          int cg = n0 + wn * 64 + j * 16 + col;
          out[(size_t)row * 1024 + cg] = acc[i][j][r];
        }
      }
  }
}

// ---------------- combine: out[tok] += Ebuf[slot0] + Ebuf[slot1] ----------------
__global__ __launch_bounds__(256)
void combine_kernel(float* __restrict__ out, const u16* __restrict__ Ebuf,
                    const int* __restrict__ slot_map){
  long long g = (long long)blockIdx.x * 256 + threadIdx.x;  // float4 index into out
  int row = (int)(g >> 8);          // 256 float4 per 1024-col row
  int c4  = (int)(g & 255);
  int s0 = slot_map[row * 2 + 0];
  int s1 = slot_map[row * 2 + 1];
  float4 v = ((float4*)out)[g];
  if (s0 >= 0){
    ushort4 a = ((const ushort4*)Ebuf)[(size_t)s0 * 256 + c4];
    v.x += bf2f(a.x); v.y += bf2f(a.y); v.z += bf2f(a.z); v.w += bf2f(a.w);
  }
  if (s1 >= 0){
    ushort4 a = ((const ushort4*)Ebuf)[(size_t)s1 * 256 + c4];
    v.x += bf2f(a.x); v.y += bf2f(a.y); v.z += bf2f(a.z); v.w += bf2f(a.w);
  }
  ((float4*)out)[g] = v;
}

extern "C" void kernel_launch(void* const* d_in, const int* in_sizes, int n_in,
                              void* d_out, int out_size, void* d_ws, size_t ws_size,
                              hipStream_t stream){
  const float* x       = (const float*)d_in[0];
  const float* gate_w  = (const float*)d_in[1];
  const float* we_gate = (const float*)d_in[2];
  const float* we_up   = (const float*)d_in[3];
  const float* we_down = (const float*)d_in[4];
  const float* ws_gate = (const float*)d_in[5];
  const float* ws_up   = (const float*)d_in[6];
  const float* ws_down = (const float*)d_in[7];
  float* out = (float*)d_out;

  // ws layout. Ebuf aliases [wg_bf .. wsu_bf] (41,943,040 B, exact): gate/up weights
  // are dead after gu_kernel; Ebuf is written by down_kernel afterwards.
  char* p = (char*)d_ws;
  u16* x_bf   = (u16*)p; p += (size_t)NTOK * HD * 2;
  u16* wg_bf  = (u16*)p; p += (size_t)NEXP * 1024 * 1024 * 2;
  u16* wu_bf  = (u16*)p; p += (size_t)NEXP * 1024 * 1024 * 2;
  u16* wsg_bf = (u16*)p; p += (size_t)2048 * 1024 * 2;
  u16* wsu_bf = (u16*)p; p += (size_t)2048 * 1024 * 2;
  u16* wd_bf  = (u16*)p; p += (size_t)NEXP * 1024 * 1024 * 2;
  u16* wsd_bf = (u16*)p; p += (size_t)1024 * 2048 * 2;
  u16* Hr     = (u16*)p; p += (size_t)NEXP * CAP * 1024 * 2;  // routed H [8*2560, 1024]
  u16* Hs     = (u16*)p; p += (size_t)NTOK * 2048 * 2;        // shared H [8192, 2048]
  int*   topk_idx   = (int*)p;   p += (size_t)NTOK * 2 * 4;
  float* topk_w     = (float*)p; p += (size_t)NTOK * 2 * 4;
  int*   tok_list   = (int*)p;   p += (size_t)NEXP * CAP * 4;
  float* w_list     = (float*)p; p += (size_t)NEXP * CAP * 4;
  int*   slot_map   = (int*)p;   p += (size_t)NTOK * 2 * 4;
  int*   chunk_hist = (int*)p;   p += 64 * NEXP * 4;
  int*   ne         = (int*)p;   p += 128;
  u16* Ebuf = wg_bf;             // alias (see note above)

  // phase 1: all casts + router (40960 blocks: 2048 router + 38912 cast)
  prep_kernel<<<dim3(40960), dim3(256), 0, stream>>>(
      x, gate_w, we_gate, we_up, we_down, ws_gate, ws_up, ws_down,
      x_bf, wg_bf, wu_bf, wd_bf, wsg_bf, wsu_bf, wsd_bf, topk_idx, topk_w);

  // phase 2: parallel capacity scan (stable)
  scan_p1<<<dim3(64), dim3(256), 0, stream>>>(topk_idx, chunk_hist);
  scan_p2<<<dim3(64), dim3(256), 0, stream>>>(topk_idx, topk_w, chunk_hist,
                                              tok_list, w_list, slot_map, ne);

  // phase 3: merged SwiGLU GEMMs (routed 2560 + shared 2048 blocks)
  gu_kernel<<<dim3(4608), dim3(256), 0, stream>>>(
      x_bf, wg_bf, wu_bf, wsg_bf, wsu_bf, Hr, Hs, tok_list, ne);

  // phase 4: merged down-proj, LPT order (shared 512 first -> out, routed 1280 -> Ebuf)
  down_kernel<<<dim3(1792), dim3(256), 0, stream>>>(
      Hr, wd_bf, Hs, wsd_bf, Ebuf, out, w_list, ne);

  // phase 5: combine routed contributions into out
  combine_kernel<<<dim3(8192), dim3(256), 0, stream>>>(out, Ebuf, slot_map);
}

// Round 7
// 487.620 us; speedup vs baseline: 1.0558x; 1.0192x over previous
//
#include <hip/hip_runtime.h>

typedef unsigned short u16;

#define NTOK 8192
#define HD   1024
#define NEXP 8
#define CAP  2560   // ceil(1.25 * 8192 * 2 / 8) == 2560 == 20 * 128 tiles exactly

typedef __bf16 bf16x8 __attribute__((ext_vector_type(8)));
typedef float  f32x4  __attribute__((ext_vector_type(4)));

__device__ __forceinline__ u16 f2bf(float f){
  union { float f; unsigned u; } v; v.f = f;
  return (u16)((v.u + 0x7fffu + ((v.u >> 16) & 1u)) >> 16);   // RNE
}
__device__ __forceinline__ float bf2f(u16 h){
  union { unsigned u; float f; } v; v.u = ((unsigned)h) << 16; return v.f;
}

__device__ __forceinline__ void async16(const void* g, void* l){
  __builtin_amdgcn_global_load_lds((__attribute__((address_space(1))) void*)(g),
                                   (__attribute__((address_space(3))) void*)(l), 16, 0, 0);
}

// ---------------- prep: router + casts needed by gu (x, wg, wu, wsg, wsu) ----------------
// blocks [0,2048): router (4 tokens/block, fp64 logits, top-2, normalized weights)
// blocks [2048,30720): segmented float4 cast of x + the 4 gate/up weight tensors
__global__ __launch_bounds__(256)
void prep_kernel(const float* __restrict__ x, const float* __restrict__ gate_w,
                 const float* __restrict__ we_gate, const float* __restrict__ we_up,
                 const float* __restrict__ ws_gate, const float* __restrict__ ws_up,
                 u16* __restrict__ x_bf, u16* __restrict__ wg_bf, u16* __restrict__ wu_bf,
                 u16* __restrict__ wsg_bf, u16* __restrict__ wsu_bf,
                 int* __restrict__ topk_idx, float* __restrict__ topk_w){
  __shared__ float gw[NEXP * HD];
  int bid = blockIdx.x;
  int t = threadIdx.x;
  if (bid < 2048){
    // ---- router ----
    for (int i = t; i < NEXP * HD; i += 256) gw[i] = gate_w[i];
    __syncthreads();
    int wave = t >> 6, l = t & 63;
    int tok = bid * 4 + wave;
    const float* xr = x + (size_t)tok * HD;
    double acc[NEXP];
#pragma unroll
    for (int e = 0; e < NEXP; e++) acc[e] = 0.0;
    for (int j = 0; j < 16; j++){
      int h = j * 64 + l;
      double xv = (double)xr[h];
#pragma unroll
      for (int e = 0; e < NEXP; e++) acc[e] += xv * (double)gw[e * HD + h];
    }
#pragma unroll
    for (int e = 0; e < NEXP; e++){
      double v = acc[e];
#pragma unroll
      for (int off = 32; off > 0; off >>= 1) v += __shfl_down(v, off, 64);
      acc[e] = v;
    }
    if (l == 0){
      int i0 = 0; double l0 = acc[0];
#pragma unroll
      for (int e = 1; e < NEXP; e++) if (acc[e] > l0){ l0 = acc[e]; i0 = e; }
      int i1 = -1; double l1 = -1e300;
#pragma unroll
      for (int e = 0; e < NEXP; e++) if (e != i0 && acc[e] > l1){ l1 = acc[e]; i1 = e; }
      double e1 = exp(l1 - l0);
      double s  = 1.0 + e1;
      topk_idx[tok * 2 + 0] = i0;
      topk_idx[tok * 2 + 1] = i1;
      topk_w [tok * 2 + 0] = (float)(1.0 / s);
      topk_w [tok * 2 + 1] = (float)(e1 / s);
    }
  } else {
    // ---- casts (segments are multiples of 256 float4s; blocks never straddle) ----
    long long g = (long long)(bid - 2048) * 256 + t;   // float4 index
    const float4* s; ushort4* d; long long off;
    if      (g <  2097152){ s = (const float4*)x;       d = (ushort4*)x_bf;   off = 0; }
    else if (g <  4194304){ s = (const float4*)we_gate; d = (ushort4*)wg_bf;  off = 2097152; }
    else if (g <  6291456){ s = (const float4*)we_up;   d = (ushort4*)wu_bf;  off = 4194304; }
    else if (g <  6815744){ s = (const float4*)ws_gate; d = (ushort4*)wsg_bf; off = 6291456; }
    else                  { s = (const float4*)ws_up;   d = (ushort4*)wsu_bf; off = 6815744; }
    long long i = g - off;
    float4 v = s[i];
    ushort4 o;
    o.x = f2bf(v.x); o.y = f2bf(v.y); o.z = f2bf(v.z); o.w = f2bf(v.w);
    d[i] = o;
  }
}

// ---------------- single-launch stable capacity scan (64 blocks) ----------------
// Each block rebuilds the full 64x8 chunk histogram via wave ballots (wave w covers
// chunks [w*16,(w+1)*16)), then ranks its own 256-slot chunk exactly as before.
__global__ __launch_bounds__(256)
void scan_kernel(const int* __restrict__ topk_idx, const float* __restrict__ topk_w,
                 int* __restrict__ tok_list, float* __restrict__ w_list,
                 int* __restrict__ slot_map, int* __restrict__ ne){
  __shared__ int hist_s[64 * NEXP];
  __shared__ int base_s[NEXP];
  __shared__ int wcnt[4 * NEXP];
  int t = threadIdx.x, w = t >> 6, l = t & 63;
  int chunk = blockIdx.x;
  for (int cc = w * 16; cc < w * 16 + 16; cc++){
    int cnt = 0;                       // lane e<8 accumulates count of expert e
#pragma unroll
    for (int g = 0; g < 4; g++){
      int eg = topk_idx[cc * 256 + g * 64 + l];
#pragma unroll
      for (int e = 0; e < NEXP; e++){
        unsigned long long m = __ballot(eg == e);
        if (l == e) cnt += __popcll(m);
      }
    }
    if (l < NEXP) hist_s[cc * NEXP + l] = cnt;
  }
  __syncthreads();
  if (t < NEXP){
    int b = 0, tot = 0;
    for (int c = 0; c < 64; c++){
      if (c == chunk) b = tot;
      tot += hist_s[c * NEXP + t];
    }
    base_s[t] = b;
    if (chunk == 0) ne[t] = tot < CAP ? tot : CAP;
  }
  int slot = chunk * 256 + t;
  int my_e = topk_idx[slot];
  float my_w = topk_w[slot];
  unsigned long long mymask = 0;
#pragma unroll
  for (int e = 0; e < NEXP; e++){
    unsigned long long m = __ballot(my_e == e);
    if (my_e == e) mymask = m;
    if (l == e) wcnt[w * NEXP + e] = __popcll(m);
  }
  __syncthreads();
  if (t < NEXP){
    int run = 0;
#pragma unroll
    for (int w2 = 0; w2 < 4; w2++){ int v = wcnt[w2 * NEXP + t]; wcnt[w2 * NEXP + t] = run; run += v; }
  }
  __syncthreads();
  int pos = base_s[my_e] + wcnt[w * NEXP + my_e] + __popcll(mymask & ((1ull << l) - 1ull));
  if (pos < CAP){
    tok_list[my_e * CAP + pos] = slot >> 1;
    w_list [my_e * CAP + pos] = my_w;
    slot_map[slot] = my_e * CAP + pos;
  } else {
    slot_map[slot] = -1;
  }
}

// ---------------- merged SwiGLU GEMM + fused wd/wsd casts ----------------
// blocks [0,2560): routed  e=bid&7 (XCD-pinned), r=bid>>3: m0=(r>>4)*128, n0=(r&15)*64
// blocks [2560,4608): shared b2: n0=(b2/64)*64, m0=(b2%64)*128
// blocks [4608,14848): float4 cast of we_down / ws_down (hidden under GEMM compute;
//                      wd/wsd are first read by the NEXT kernel, so no ordering issue)
__global__ __launch_bounds__(256)
void gu_kernel(const u16* __restrict__ x_bf,
               const u16* __restrict__ wg, const u16* __restrict__ wu,
               const u16* __restrict__ wsg, const u16* __restrict__ wsu,
               u16* __restrict__ Hr, u16* __restrict__ Hs,
               const int* __restrict__ tok_list, const int* __restrict__ ne,
               const float* __restrict__ we_down, const float* __restrict__ ws_down,
               u16* __restrict__ wd_bf, u16* __restrict__ wsd_bf)
{
  __shared__ u16 As[128 * 64];
  __shared__ u16 Bs[128 * 64];

  const int bid = blockIdx.x;
  const int tid = threadIdx.x;

  if (bid >= 4608){
    // ---- fused down-weight casts ----
    long long g = (long long)(bid - 4608) * 256 + tid;   // float4 index
    const float4* s; ushort4* d; long long off;
    if (g < 2097152){ s = (const float4*)we_down; d = (ushort4*)wd_bf;  off = 0; }
    else            { s = (const float4*)ws_down; d = (ushort4*)wsd_bf; off = 2097152; }
    long long i = g - off;
    float4 v = s[i];
    ushort4 o;
    o.x = f2bf(v.x); o.y = f2bf(v.y); o.z = f2bf(v.z); o.w = f2bf(v.w);
    d[i] = o;
    return;
  }

  const bool routed = bid < 2560;
  int m0, n0, ldc, n_valid;
  const u16 *B0, *B1;
  u16* C;
  const int* tl = nullptr;
  if (routed){
    int e = bid & 7, r = bid >> 3;
    m0 = (r >> 4) * 128; n0 = (r & 15) * 64;
    B0 = wg + (size_t)e * (1024 * 1024);
    B1 = wu + (size_t)e * (1024 * 1024);
    C  = Hr + (size_t)e * (CAP * 1024);
    ldc = 1024;
    n_valid = ne[e];
    tl = tok_list + e * CAP;
    if (m0 >= n_valid) return;
  } else {
    int b2 = bid - 2560;
    n0 = (b2 / 64) * 64; m0 = (b2 % 64) * 128;
    B0 = wsg; B1 = wsu; C = Hs; ldc = 2048; n_valid = 1 << 30;
  }

  const int wv  = tid >> 6;
  const int l   = tid & 63;
  const int lr  = l >> 3;             // row within 8-row chunk
  const int cb  = (l & 7) ^ lr;       // XOR-swizzled col-block (16B units)

  const u16* aptr[4];
  const u16* bptr[4];
#pragma unroll
  for (int i = 0; i < 4; i++){
    int chunk = i * 4 + wv;
    int arow  = m0 + chunk * 8 + lr;
    if (routed){
      int r2 = arow < n_valid ? arow : (n_valid - 1);
      aptr[i] = x_bf + (size_t)tl[r2] * 1024 + cb * 8;
    } else {
      aptr[i] = x_bf + (size_t)arow * 1024 + cb * 8;
    }
    int rn = chunk * 8 + lr;          // B tile row 0..127
    int w  = rn >> 6;                 // which wave-half of N
    int jq = (rn >> 4) & 3;           // 0,1 = gate ; 2,3 = up (uniform per chunk)
    int rl = rn & 15;
    int icol = n0 + w * 32 + (jq & 1) * 16 + rl;
    bptr[i] = ((jq < 2) ? B0 : B1) + (size_t)icol * 1024 + cb * 8;
  }

  const int wm = wv & 1, wn = wv >> 1;
  const int col = l & 15, quad = l >> 4;
  const int rr = col & 7, ch = col >> 3;

  f32x4 acc[4][4];
#pragma unroll
  for (int i = 0; i < 4; i++)
#pragma unroll
    for (int j = 0; j < 4; j++)
      acc[i][j] = (f32x4){0.f, 0.f, 0.f, 0.f};

  for (int k0 = 0; k0 < 1024; k0 += 64){
#pragma unroll
    for (int i = 0; i < 4; i++){
      int chunk = i * 4 + wv;
      async16(aptr[i] + k0, &As[chunk * 512 + l * 8]);
      async16(bptr[i] + k0, &Bs[chunk * 512 + l * 8]);
    }
    __syncthreads();
#pragma unroll
    for (int s = 0; s < 2; s++){
      const int so = (rr * 8 + ((quad + s * 4) ^ rr)) * 8;   // swizzled fragment offset
      bf16x8 a[4], b[4];
#pragma unroll
      for (int i = 0; i < 4; i++) a[i] = *(const bf16x8*)&As[(wm * 8 + i * 2 + ch) * 512 + so];
#pragma unroll
      for (int j = 0; j < 4; j++) b[j] = *(const bf16x8*)&Bs[(wn * 8 + j * 2 + ch) * 512 + so];
#pragma unroll
      for (int i = 0; i < 4; i++)
#pragma unroll
        for (int j = 0; j < 4; j++)
          acc[i][j] = __builtin_amdgcn_mfma_f32_16x16x32_bf16(a[i], b[j], acc[i][j], 0, 0, 0);
    }
    __syncthreads();
  }

  // epilogue: silu(g)*u -> bf16
#pragma unroll
  for (int i = 0; i < 4; i++)
#pragma unroll
    for (int r = 0; r < 4; r++){
      int row = m0 + wm * 64 + i * 16 + quad * 4 + r;
#pragma unroll
      for (int j = 0; j < 2; j++){
        int cg = n0 + wn * 32 + j * 16 + col;
        float g = acc[i][j][r], u = acc[i][j + 2][r];
        float h = (g / (1.f + __expf(-g))) * u;
        C[(size_t)row * ldc + cg] = f2bf(h);
      }
    }
}

// ---------------- merged down-proj (r4 order): routed -> Ebuf, shared -> out ----------------
// blocks [0,1280): routed e=bid&7 (XCD-pinned), r=bid>>3: m0=(r>>3)*128, n0=(r&7)*128, K=1024
// blocks [1280,1792): shared b2=bid-1280: n0=(b2&7)*128, m0=(b2>>3)*128, K=2048
__global__ __launch_bounds__(256)
void down_kernel(const u16* __restrict__ Hr, const u16* __restrict__ wd,
                 const u16* __restrict__ Hs, const u16* __restrict__ wsd,
                 u16* __restrict__ Ebuf, float* __restrict__ out,
                 const float* __restrict__ w_list, const int* __restrict__ ne)
{
  __shared__ u16 As[128 * 64];
  __shared__ u16 Bs[128 * 64];

  const int bid = blockIdx.x;
  const bool routed = bid < 1280;
  int m0, n0, n_valid, K, e = 0;
  const u16 *Ab, *Bb;
  if (routed){
    e = bid & 7; int r = bid >> 3;
    m0 = (r >> 3) * 128; n0 = (r & 7) * 128;
    Ab = Hr + (size_t)e * (CAP * 1024);
    Bb = wd + (size_t)e * (1024 * 1024);
    K = 1024;
    n_valid = ne[e];
    if (m0 >= n_valid) return;
  } else {
    int b2 = bid - 1280;
    n0 = (b2 & 7) * 128; m0 = (b2 >> 3) * 128;
    Ab = Hs; Bb = wsd; K = 2048; n_valid = 1 << 30;
  }

  const int tid = threadIdx.x;
  const int wv  = tid >> 6;
  const int l   = tid & 63;
  const int lr  = l >> 3;
  const int cb  = (l & 7) ^ lr;

  const u16* aptr[4];
  const u16* bptr[4];
#pragma unroll
  for (int i = 0; i < 4; i++){
    int chunk = i * 4 + wv;
    aptr[i] = Ab + (size_t)(m0 + chunk * 8 + lr) * K + cb * 8;
    bptr[i] = Bb + (size_t)(n0 + chunk * 8 + lr) * K + cb * 8;
  }

  const int wm = wv & 1, wn = wv >> 1;
  const int col = l & 15, quad = l >> 4;
  const int rr = col & 7, ch = col >> 3;

  f32x4 acc[4][4];
#pragma unroll
  for (int i = 0; i < 4; i++)
#pragma unroll
    for (int j = 0; j < 4; j++)
      acc[i][j] = (f32x4){0.f, 0.f, 0.f, 0.f};

  for (int k0 = 0; k0 < K; k0 += 64){
#pragma unroll
    for (int i = 0; i < 4; i++){
      int chunk = i * 4 + wv;
      async16(aptr[i] + k0, &As[chunk * 512 + l * 8]);
      async16(bptr[i] + k0, &Bs[chunk * 512 + l * 8]);
    }
    __syncthreads();
#pragma unroll
    for (int s = 0; s < 2; s++){
      const int so = (rr * 8 + ((quad + s * 4) ^ rr)) * 8;
      bf16x8 a[4], b[4];
#pragma unroll
      for (int i = 0; i < 4; i++) a[i] = *(const bf16x8*)&As[(wm * 8 + i * 2 + ch) * 512 + so];
#pragma unroll
      for (int j = 0; j < 4; j++) b[j] = *(const bf16x8*)&Bs[(wn * 8 + j * 2 + ch) * 512 + so];
#pragma unroll
      for (int i = 0; i < 4; i++)
#pragma unroll
        for (int j = 0; j < 4; j++)
          acc[i][j] = __builtin_amdgcn_mfma_f32_16x16x32_bf16(a[i], b[j], acc[i][j], 0, 0, 0);
    }
    __syncthreads();
  }

  if (routed){
    u16* C = Ebuf + (size_t)e * (CAP * 1024);
    const float* wl = w_list + e * CAP;
#pragma unroll
    for (int i = 0; i < 4; i++)
#pragma unroll
      for (int r = 0; r < 4; r++){
        int row = m0 + wm * 64 + i * 16 + quad * 4 + r;
        if (row < n_valid){
          float wgt = wl[row];
#pragma unroll
          for (int j = 0; j < 4; j++){
            int cg = n0 + wn * 64 + j * 16 + col;
            C[(size_t)row * 1024 + cg] = f2bf(wgt * acc[i][j][r]);
          }
        }
      }
  } else {
#pragma unroll
    for (int i = 0; i < 4; i++)
#pragma unroll
      for (int r = 0; r < 4; r++){
        int row = m0 + wm * 64 + i * 16 + quad * 4 + r;
#pragma unroll
        for (int j = 0; j < 4; j++){
          int cg = n0 + wn * 64 + j * 16 + col;
          out[(size_t)row * 1024 + cg] = acc[i][j][r];
        }
      }
  }
}

// ---------------- combine: out[tok] += Ebuf[slot0] + Ebuf[slot1] ----------------
__global__ __launch_bounds__(256)
void combine_kernel(float* __restrict__ out, const u16* __restrict__ Ebuf,
                    const int* __restrict__ slot_map){
  long long g = (long long)blockIdx.x * 256 + threadIdx.x;  // float4 index into out
  int row = (int)(g >> 8);          // 256 float4 per 1024-col row
  int c4  = (int)(g & 255);
  int s0 = slot_map[row * 2 + 0];
  int s1 = slot_map[row * 2 + 1];
  float4 v = ((float4*)out)[g];
  if (s0 >= 0){
    ushort4 a = ((const ushort4*)Ebuf)[(size_t)s0 * 256 + c4];
    v.x += bf2f(a.x); v.y += bf2f(a.y); v.z += bf2f(a.z); v.w += bf2f(a.w);
  }
  if (s1 >= 0){
    ushort4 a = ((const ushort4*)Ebuf)[(size_t)s1 * 256 + c4];
    v.x += bf2f(a.x); v.y += bf2f(a.y); v.z += bf2f(a.z); v.w += bf2f(a.w);
  }
  ((float4*)out)[g] = v;
}

extern "C" void kernel_launch(void* const* d_in, const int* in_sizes, int n_in,
                              void* d_out, int out_size, void* d_ws, size_t ws_size,
                              hipStream_t stream){
  const float* x       = (const float*)d_in[0];
  const float* gate_w  = (const float*)d_in[1];
  const float* we_gate = (const float*)d_in[2];
  const float* we_up   = (const float*)d_in[3];
  const float* we_down = (const float*)d_in[4];
  const float* ws_gate = (const float*)d_in[5];
  const float* ws_up   = (const float*)d_in[6];
  const float* ws_down = (const float*)d_in[7];
  float* out = (float*)d_out;

  // ws layout. Ebuf aliases [wg_bf .. wsu_bf] (41,943,040 B, exact): gate/up weights
  // are dead after gu_kernel's GEMM blocks; Ebuf is written by down_kernel afterwards.
  // wd_bf/wsd_bf are separate storage (written during gu by the fused cast blocks).
  char* p = (char*)d_ws;
  u16* x_bf   = (u16*)p; p += (size_t)NTOK * HD * 2;
  u16* wg_bf  = (u16*)p; p += (size_t)NEXP * 1024 * 1024 * 2;
  u16* wu_bf  = (u16*)p; p += (size_t)NEXP * 1024 * 1024 * 2;
  u16* wsg_bf = (u16*)p; p += (size_t)2048 * 1024 * 2;
  u16* wsu_bf = (u16*)p; p += (size_t)2048 * 1024 * 2;
  u16* wd_bf  = (u16*)p; p += (size_t)NEXP * 1024 * 1024 * 2;
  u16* wsd_bf = (u16*)p; p += (size_t)1024 * 2048 * 2;
  u16* Hr     = (u16*)p; p += (size_t)NEXP * CAP * 1024 * 2;  // routed H [8*2560, 1024]
  u16* Hs     = (u16*)p; p += (size_t)NTOK * 2048 * 2;        // shared H [8192, 2048]
  int*   topk_idx   = (int*)p;   p += (size_t)NTOK * 2 * 4;
  float* topk_w     = (float*)p; p += (size_t)NTOK * 2 * 4;
  int*   tok_list   = (int*)p;   p += (size_t)NEXP * CAP * 4;
  float* w_list     = (float*)p; p += (size_t)NEXP * CAP * 4;
  int*   slot_map   = (int*)p;   p += (size_t)NTOK * 2 * 4;
  int*   ne         = (int*)p;   p += 128;
  u16* Ebuf = wg_bf;             // alias (see note above)

  // phase 1: router + gu-phase casts (30720 blocks: 2048 router + 28672 cast)
  prep_kernel<<<dim3(30720), dim3(256), 0, stream>>>(
      x, gate_w, we_gate, we_up, ws_gate, ws_up,
      x_bf, wg_bf, wu_bf, wsg_bf, wsu_bf, topk_idx, topk_w);

  // phase 2: single-launch stable capacity scan
  scan_kernel<<<dim3(64), dim3(256), 0, stream>>>(topk_idx, topk_w,
                                                  tok_list, w_list, slot_map, ne);

  // phase 3: merged SwiGLU GEMMs (4608 blocks) + fused wd/wsd casts (10240 blocks)
  gu_kernel<<<dim3(14848), dim3(256), 0, stream>>>(
      x_bf, wg_bf, wu_bf, wsg_bf, wsu_bf, Hr, Hs, tok_list, ne,
      we_down, ws_down, wd_bf, wsd_bf);

  // phase 4: merged down-proj (routed 1280 -> Ebuf, shared 512 -> out; r4 order)
  down_kernel<<<dim3(1792), dim3(256), 0, stream>>>(
      Hr, wd_bf, Hs, wsd_bf, Ebuf, out, w_list, ne);

  // phase 5: combine routed contributions into out
  combine_kernel<<<dim3(8192), dim3(256), 0, stream>>>(out, Ebuf, slot_map);
}